// Round 1
// baseline (638.467 us; speedup 1.0000x reference)
//
#include <hip/hip_runtime.h>
#include <hip/hip_bf16.h>
#include <hip/hip_fp16.h>

#define BATCH 16384
#define NM 9
#define ND 512
#define BM 64
#define NTHREADS 512

typedef __bf16 bf16x8 __attribute__((ext_vector_type(8)));
typedef float  f32x4  __attribute__((ext_vector_type(4)));

// ---------------- K0: W[m][d][e] (fp32) -> WT[m][e][d] (bf16) ----------------
__global__ __launch_bounds__(256)
void prep_weights(const float* __restrict__ Wi, const float* __restrict__ We,
                  __hip_bfloat16* __restrict__ WiT, __hip_bfloat16* __restrict__ WeT) {
  __shared__ float tile[32][33];
  const int z = blockIdx.z;
  const float* src;
  __hip_bfloat16* dst;
  if (z < NM) { src = Wi + (size_t)z * ND * ND;        dst = WiT + (size_t)z * ND * ND; }
  else        { src = We + (size_t)(z - NM) * ND * ND; dst = WeT + (size_t)(z - NM) * ND * ND; }
  const int d0 = blockIdx.y * 32;
  const int e0 = blockIdx.x * 32;
  const int tx = threadIdx.x, ty = threadIdx.y;
  #pragma unroll
  for (int i = 0; i < 4; ++i)
    tile[ty + i * 8][tx] = src[(size_t)(d0 + ty + i * 8) * ND + e0 + tx];
  __syncthreads();
  #pragma unroll
  for (int i = 0; i < 4; ++i)
    dst[(size_t)(e0 + ty + i * 8) * ND + d0 + tx] = __float2bfloat16(tile[tx][ty + i * 8]);
}

// ---------------- K1: per-branch dual GEMM + sigmoid/L1 gate + relu ----------------
// grid.x = BATCH/BM ; 512 threads = 8 waves, each wave owns 64 output cols.
// For each m: stage X tile once, pass 0: t_i = X@Wi -> alpha, pass 1: g = relu(alpha * (X@We) + be).
// g stored as fp16 into the d_out slot of the same batch rows (overwritten later by K2).
__global__ __launch_bounds__(NTHREADS)
void gemm_kernel(const float* __restrict__ x,
                 const __hip_bfloat16* __restrict__ WiT,
                 const __hip_bfloat16* __restrict__ WeT,
                 const float* __restrict__ bi,
                 const float* __restrict__ be,
                 float* __restrict__ out) {
  __shared__ __hip_bfloat16 Xs[BM][ND + 8];   // +8 pad: 1040B row stride, 16B aligned, 2-way banks
  __shared__ float alphaW[8][BM];
  __shared__ float alphaV[BM];

  const int tid  = threadIdx.x;
  const int wave = tid >> 6;
  const int lane = tid & 63;
  const int l15  = lane & 15;
  const int l4   = lane >> 4;
  const int b0   = blockIdx.x * BM;
  const int wn0  = wave * 64;

  float* alpha_out = out + (size_t)BATCH * NM * ND;

  for (int m = 0; m < NM; ++m) {
    __syncthreads();  // protect Xs from prior-iteration readers
    // ---- stage X tile: fp32 global -> bf16 LDS ----
    #pragma unroll
    for (int it = 0; it < (BM * ND / 4) / NTHREADS; ++it) {
      int idx = it * NTHREADS + tid;
      int r   = idx >> 7;
      int c4  = (idx & 127) * 4;
      float4 v = *(const float4*)(x + (size_t)(b0 + r) * (NM * ND) + m * ND + c4);
      union { ushort4 u; __hip_bfloat16 h[4]; } p;
      p.h[0] = __float2bfloat16(v.x);
      p.h[1] = __float2bfloat16(v.y);
      p.h[2] = __float2bfloat16(v.z);
      p.h[3] = __float2bfloat16(v.w);
      *(ushort4*)&Xs[r][c4] = p.u;
    }
    __syncthreads();

    float biv[4], bev[4];
    #pragma unroll
    for (int nt = 0; nt < 4; ++nt) {
      biv[nt] = bi[m * ND + wn0 + nt * 16 + l15];
      bev[nt] = be[m * ND + wn0 + nt * 16 + l15];
    }

    for (int pass = 0; pass < 2; ++pass) {
      const __hip_bfloat16* wbase = (pass ? WeT : WiT) + (size_t)m * ND * ND;
      f32x4 acc[4][4];
      #pragma unroll
      for (int a = 0; a < 4; ++a)
        #pragma unroll
        for (int c = 0; c < 4; ++c) acc[a][c] = (f32x4){0.f, 0.f, 0.f, 0.f};

      for (int kt = 0; kt < ND / 32; ++kt) {
        const int kbase = kt * 32 + l4 * 8;
        bf16x8 af[4], bfr[4];
        #pragma unroll
        for (int mt = 0; mt < 4; ++mt)
          af[mt] = *(const bf16x8*)&Xs[mt * 16 + l15][kbase];
        #pragma unroll
        for (int nt = 0; nt < 4; ++nt)
          bfr[nt] = *(const bf16x8*)(wbase + (size_t)(wn0 + nt * 16 + l15) * ND + kbase);
        #pragma unroll
        for (int mt = 0; mt < 4; ++mt)
          #pragma unroll
          for (int nt = 0; nt < 4; ++nt)
            acc[mt][nt] = __builtin_amdgcn_mfma_f32_16x16x32_bf16(af[mt], bfr[nt], acc[mt][nt], 0, 0, 0);
      }

      if (pass == 0) {
        // sigmoid + row-sum (L1 norm of f; sigmoid > 0 so |f| = f)
        #pragma unroll
        for (int mt = 0; mt < 4; ++mt)
          #pragma unroll
          for (int r = 0; r < 4; ++r) {
            float s = 0.f;
            #pragma unroll
            for (int nt = 0; nt < 4; ++nt) {
              float t = acc[mt][nt][r] + biv[nt];
              s += 1.f / (1.f + __expf(-t));
            }
            s += __shfl_xor(s, 1, 16);
            s += __shfl_xor(s, 2, 16);
            s += __shfl_xor(s, 4, 16);
            s += __shfl_xor(s, 8, 16);
            if (l15 == 0) alphaW[wave][mt * 16 + l4 * 4 + r] = s;
          }
        __syncthreads();
        if (tid < BM) {
          float a = 0.f;
          #pragma unroll
          for (int w = 0; w < 8; ++w) a += alphaW[w][tid];
          alphaV[tid] = a;
          alpha_out[(size_t)(b0 + tid) * NM + m] = a;
        }
        __syncthreads();
      } else {
        // g = relu(alpha * t_e + be), store fp16 into out-region slot of row b
        #pragma unroll
        for (int mt = 0; mt < 4; ++mt)
          #pragma unroll
          for (int r = 0; r < 4; ++r) {
            const int row = mt * 16 + l4 * 4 + r;
            __half* gd = (__half*)((char*)out + (size_t)(b0 + row) * (NM * ND * 4)) + m * ND;
            const float al = alphaV[row];
            #pragma unroll
            for (int nt = 0; nt < 4; ++nt) {
              float t = fmaxf(al * acc[mt][nt][r] + bev[nt], 0.f);
              gd[wn0 + nt * 16 + l15] = __float2half(t);
            }
          }
      }
    }
  }
}

// ---------------- K2: inter-branch affinity + aggregation ----------------
__global__ __launch_bounds__(256)
void inter_kernel(float* __restrict__ out) {
  __shared__ float gs[NM][ND + 8];
  __shared__ float Gr[45];
  __shared__ float aff[NM][NM];
  const int b = blockIdx.x;
  const int tid = threadIdx.x;
  const __half* gsrc = (const __half*)((const char*)out + (size_t)b * (NM * ND * 4));

  for (int i = tid; i < NM * ND / 4; i += 256) {
    union { ushort4 u; __half h[4]; } p;
    p.u = *(const ushort4*)((const ushort*)gsrc + (size_t)i * 4);
    const int m = i >> 7;
    const int e = (i & 127) * 4;
    #pragma unroll
    for (int j = 0; j < 4; ++j) gs[m][e + j] = __half2float(p.h[j]);
  }
  __syncthreads();

  // 45 upper-triangular pair dot-products (incl. diagonal = sq)
  const int wave = tid >> 6, lane = tid & 63;
  for (int pr = wave; pr < 45; pr += 4) {
    int a = 0, q = pr;
    while (q >= NM - a) { q -= NM - a; ++a; }
    const int bb = a + q;
    float s = 0.f;
    #pragma unroll
    for (int j = 0; j < 8; ++j) s += gs[a][lane + 64 * j] * gs[bb][lane + 64 * j];
    #pragma unroll
    for (int off = 1; off < 64; off <<= 1) s += __shfl_xor(s, off, 64);
    if (lane == 0) Gr[pr] = s;
  }
  __syncthreads();

  if (tid < NM * NM) {
    const int mm = tid / NM, nn = tid % NM;
    float v = 0.f;
    if (mm != nn) {
      const int a = mm < nn ? mm : nn;
      const int c = mm < nn ? nn : mm;
      auto tri = [](int t) { return t * NM - (t * (t - 1)) / 2; };
      float d2 = Gr[tri(mm)] + Gr[tri(nn)] - 2.f * Gr[tri(a) + (c - a)];
      d2 = fmaxf(d2, 0.f);
      v = tanhf(sqrtf(d2));
    }
    aff[tid / NM][tid % NM] = v;
  }
  __syncthreads();

  float* od = out + (size_t)b * (NM * ND);
  for (int i = tid; i < NM * ND; i += 256) {
    const int mm = i >> 9, e = i & 511;
    float acc = 0.f;
    #pragma unroll
    for (int n = 0; n < NM; ++n) acc += aff[mm][n] * gs[n][e];
    od[i] = 0.5f * (gs[mm][e] + acc);
  }
}

extern "C" void kernel_launch(void* const* d_in, const int* in_sizes, int n_in,
                              void* d_out, int out_size, void* d_ws, size_t ws_size,
                              hipStream_t stream) {
  const float* x  = (const float*)d_in[0];
  const float* Wi = (const float*)d_in[1];
  const float* bi = (const float*)d_in[2];
  const float* We = (const float*)d_in[3];
  const float* be = (const float*)d_in[4];
  float* out = (float*)d_out;

  __hip_bfloat16* WiT = (__hip_bfloat16*)d_ws;
  __hip_bfloat16* WeT = WiT + (size_t)NM * ND * ND;

  prep_weights<<<dim3(ND / 32, ND / 32, 2 * NM), dim3(32, 8), 0, stream>>>(Wi, We, WiT, WeT);
  gemm_kernel<<<BATCH / BM, NTHREADS, 0, stream>>>(x, WiT, WeT, bi, be, out);
  inter_kernel<<<BATCH, 256, 0, stream>>>(out);
}

// Round 2
// 594.354 us; speedup vs baseline: 1.0742x; 1.0742x over previous
//
#include <hip/hip_runtime.h>
#include <hip/hip_bf16.h>
#include <hip/hip_fp16.h>

#define BATCH 16384
#define NM 9
#define ND 512
#define BM 64
#define NTHREADS 512

typedef __bf16 bf16x8 __attribute__((ext_vector_type(8)));
typedef float  f32x4  __attribute__((ext_vector_type(4)));

// ---------------- K0: W[m][d][e] (fp32) -> WT[m][e][d] (bf16) ----------------
__global__ __launch_bounds__(256)
void prep_weights(const float* __restrict__ Wi, const float* __restrict__ We,
                  __hip_bfloat16* __restrict__ WiT, __hip_bfloat16* __restrict__ WeT) {
  __shared__ float tile[32][33];
  const int z = blockIdx.z;
  const float* src;
  __hip_bfloat16* dst;
  if (z < NM) { src = Wi + (size_t)z * ND * ND;        dst = WiT + (size_t)z * ND * ND; }
  else        { src = We + (size_t)(z - NM) * ND * ND; dst = WeT + (size_t)(z - NM) * ND * ND; }
  const int d0 = blockIdx.y * 32;
  const int e0 = blockIdx.x * 32;
  const int tx = threadIdx.x, ty = threadIdx.y;
  #pragma unroll
  for (int i = 0; i < 4; ++i)
    tile[ty + i * 8][tx] = src[(size_t)(d0 + ty + i * 8) * ND + e0 + tx];
  __syncthreads();
  #pragma unroll
  for (int i = 0; i < 4; ++i)
    dst[(size_t)(e0 + ty + i * 8) * ND + d0 + tx] = __float2bfloat16(tile[tx][ty + i * 8]);
}

// ---------------- K1: per-(btile,m) dual GEMM + sigmoid/L1 gate + relu ----------------
// grid = (BATCH/BM, NM); 512 threads = 8 waves, each wave owns 64 output cols.
// Stage X tile once; pass 0: t_i = X@Wi -> alpha; pass 1: g = relu(alpha*(X@We)+be) stored fp16.
__global__ __launch_bounds__(NTHREADS, 4)
void gemm_kernel(const float* __restrict__ x,
                 const __hip_bfloat16* __restrict__ WiT,
                 const __hip_bfloat16* __restrict__ WeT,
                 const float* __restrict__ bi,
                 const float* __restrict__ be,
                 float* __restrict__ out) {
  __shared__ __hip_bfloat16 Xs[BM][ND + 8];   // 1040B row stride: 16B aligned, 2-way banks
  __shared__ float alphaW[8][BM];
  __shared__ float alphaV[BM];

  const int tid  = threadIdx.x;
  const int wave = tid >> 6;
  const int lane = tid & 63;
  const int l15  = lane & 15;
  const int l4   = lane >> 4;
  const int m    = blockIdx.y;
  const int b0   = blockIdx.x * BM;
  const int wn0  = wave * 64;

  float* alpha_out = out + (size_t)BATCH * NM * ND;

  // ---- stage X tile: fp32 global -> bf16 LDS (once per block) ----
  #pragma unroll
  for (int it = 0; it < (BM * ND / 4) / NTHREADS; ++it) {
    int idx = it * NTHREADS + tid;
    int r   = idx >> 7;
    int c4  = (idx & 127) * 4;
    float4 v = *(const float4*)(x + (size_t)(b0 + r) * (NM * ND) + m * ND + c4);
    union { ushort4 u; __hip_bfloat16 h[4]; } p;
    p.h[0] = __float2bfloat16(v.x);
    p.h[1] = __float2bfloat16(v.y);
    p.h[2] = __float2bfloat16(v.z);
    p.h[3] = __float2bfloat16(v.w);
    *(ushort4*)&Xs[r][c4] = p.u;
  }
  __syncthreads();

  for (int pass = 0; pass < 2; ++pass) {
    const __hip_bfloat16* wbase = (pass ? WeT : WiT) + (size_t)m * ND * ND;
    const __hip_bfloat16* wp[4];
    #pragma unroll
    for (int nt = 0; nt < 4; ++nt)
      wp[nt] = wbase + (size_t)(wn0 + nt * 16 + l15) * ND + l4 * 8;

    f32x4 acc[4][4];
    #pragma unroll
    for (int a = 0; a < 4; ++a)
      #pragma unroll
      for (int c = 0; c < 4; ++c) acc[a][c] = (f32x4){0.f, 0.f, 0.f, 0.f};

    bf16x8 bcur[4], bnext[4];
    #pragma unroll
    for (int nt = 0; nt < 4; ++nt) bcur[nt] = *(const bf16x8*)(wp[nt]);

    #pragma unroll
    for (int kt = 0; kt < ND / 32; ++kt) {
      // prefetch next k-step's B fragments (imm-offset loads off per-lane bases)
      if (kt < ND / 32 - 1) {
        #pragma unroll
        for (int nt = 0; nt < 4; ++nt)
          bnext[nt] = *(const bf16x8*)(wp[nt] + (kt + 1) * 32);
      }
      bf16x8 af[4];
      const int kbase = kt * 32 + l4 * 8;
      #pragma unroll
      for (int mt = 0; mt < 4; ++mt)
        af[mt] = *(const bf16x8*)&Xs[mt * 16 + l15][kbase];
      #pragma unroll
      for (int mt = 0; mt < 4; ++mt)
        #pragma unroll
        for (int nt = 0; nt < 4; ++nt)
          acc[mt][nt] = __builtin_amdgcn_mfma_f32_16x16x32_bf16(af[mt], bcur[nt], acc[mt][nt], 0, 0, 0);
      #pragma unroll
      for (int nt = 0; nt < 4; ++nt) bcur[nt] = bnext[nt];
    }

    if (pass == 0) {
      // sigmoid + row-sum (sigmoid > 0 so |f| = f)
      float biv[4];
      #pragma unroll
      for (int nt = 0; nt < 4; ++nt) biv[nt] = bi[m * ND + wn0 + nt * 16 + l15];
      #pragma unroll
      for (int mt = 0; mt < 4; ++mt)
        #pragma unroll
        for (int r = 0; r < 4; ++r) {
          float s = 0.f;
          #pragma unroll
          for (int nt = 0; nt < 4; ++nt) {
            float t = acc[mt][nt][r] + biv[nt];
            s += 1.f / (1.f + __expf(-t));
          }
          s += __shfl_xor(s, 1, 16);
          s += __shfl_xor(s, 2, 16);
          s += __shfl_xor(s, 4, 16);
          s += __shfl_xor(s, 8, 16);
          if (l15 == 0) alphaW[wave][mt * 16 + l4 * 4 + r] = s;
        }
      __syncthreads();
      if (tid < BM) {
        float a = 0.f;
        #pragma unroll
        for (int w = 0; w < 8; ++w) a += alphaW[w][tid];
        alphaV[tid] = a;
        alpha_out[(size_t)(b0 + tid) * NM + m] = a;
      }
      __syncthreads();
    } else {
      // g = relu(alpha * t_e + be), stored fp16 into the out slot of row b
      float bev[4];
      #pragma unroll
      for (int nt = 0; nt < 4; ++nt) bev[nt] = be[m * ND + wn0 + nt * 16 + l15];
      #pragma unroll
      for (int mt = 0; mt < 4; ++mt)
        #pragma unroll
        for (int r = 0; r < 4; ++r) {
          const int row = mt * 16 + l4 * 4 + r;
          __half* gd = (__half*)((char*)out + (size_t)(b0 + row) * (NM * ND * 4)) + m * ND;
          const float al = alphaV[row];
          #pragma unroll
          for (int nt = 0; nt < 4; ++nt) {
            float t = fmaxf(al * acc[mt][nt][r] + bev[nt], 0.f);
            gd[wn0 + nt * 16 + l15] = __float2half(t);
          }
        }
    }
  }
}

// ---------------- K2: inter-branch affinity + aggregation ----------------
__global__ __launch_bounds__(256)
void inter_kernel(float* __restrict__ out) {
  __shared__ float gs[NM][ND + 8];
  __shared__ float Gr[45];
  __shared__ float aff[NM][NM];
  const int b = blockIdx.x;
  const int tid = threadIdx.x;
  const __half* gsrc = (const __half*)((const char*)out + (size_t)b * (NM * ND * 4));

  for (int i = tid; i < NM * ND / 4; i += 256) {
    union { ushort4 u; __half h[4]; } p;
    p.u = *(const ushort4*)((const ushort*)gsrc + (size_t)i * 4);
    const int m = i >> 7;
    const int e = (i & 127) * 4;
    #pragma unroll
    for (int j = 0; j < 4; ++j) gs[m][e + j] = __half2float(p.h[j]);
  }
  __syncthreads();

  // 45 upper-triangular pair dot-products (incl. diagonal = sq)
  const int wave = tid >> 6, lane = tid & 63;
  for (int pr = wave; pr < 45; pr += 4) {
    int a = 0, q = pr;
    while (q >= NM - a) { q -= NM - a; ++a; }
    const int bb = a + q;
    float s = 0.f;
    #pragma unroll
    for (int j = 0; j < 8; ++j) s += gs[a][lane + 64 * j] * gs[bb][lane + 64 * j];
    #pragma unroll
    for (int off = 1; off < 64; off <<= 1) s += __shfl_xor(s, off, 64);
    if (lane == 0) Gr[pr] = s;
  }
  __syncthreads();

  if (tid < NM * NM) {
    const int mm = tid / NM, nn = tid % NM;
    float v = 0.f;
    if (mm != nn) {
      const int a = mm < nn ? mm : nn;
      const int c = mm < nn ? nn : mm;
      auto tri = [](int t) { return t * NM - (t * (t - 1)) / 2; };
      float d2 = Gr[tri(mm)] + Gr[tri(nn)] - 2.f * Gr[tri(a) + (c - a)];
      d2 = fmaxf(d2, 0.f);
      v = tanhf(sqrtf(d2));
    }
    aff[tid / NM][tid % NM] = v;
  }
  __syncthreads();

  float* od = out + (size_t)b * (NM * ND);
  for (int i = tid; i < NM * ND / 4; i += 256) {
    const int mm = i >> 7;
    const int e4 = (i & 127) * 4;
    float4 r;
    #pragma unroll
    for (int j = 0; j < 4; ++j) {
      const int e = e4 + j;
      float acc = 0.f;
      #pragma unroll
      for (int n = 0; n < NM; ++n) acc += aff[mm][n] * gs[n][e];
      ((float*)&r)[j] = 0.5f * (gs[mm][e] + acc);
    }
    *(float4*)(od + (size_t)mm * ND + e4) = r;
  }
}

extern "C" void kernel_launch(void* const* d_in, const int* in_sizes, int n_in,
                              void* d_out, int out_size, void* d_ws, size_t ws_size,
                              hipStream_t stream) {
  const float* x  = (const float*)d_in[0];
  const float* Wi = (const float*)d_in[1];
  const float* bi = (const float*)d_in[2];
  const float* We = (const float*)d_in[3];
  const float* be = (const float*)d_in[4];
  float* out = (float*)d_out;

  __hip_bfloat16* WiT = (__hip_bfloat16*)d_ws;
  __hip_bfloat16* WeT = WiT + (size_t)NM * ND * ND;

  prep_weights<<<dim3(ND / 32, ND / 32, 2 * NM), dim3(32, 8), 0, stream>>>(Wi, We, WiT, WeT);
  gemm_kernel<<<dim3(BATCH / BM, NM), NTHREADS, 0, stream>>>(x, WiT, WeT, bi, be, out);
  inter_kernel<<<BATCH, 256, 0, stream>>>(out);
}

// Round 4
// 512.546 us; speedup vs baseline: 1.2457x; 1.1596x over previous
//
#include <hip/hip_runtime.h>
#include <hip/hip_bf16.h>
#include <hip/hip_fp16.h>

#define BATCH 16384
#define NM 9
#define ND 512
#define BM 64
#define NTHREADS 512

typedef __bf16 bf16x8 __attribute__((ext_vector_type(8)));
typedef float  f32x4  __attribute__((ext_vector_type(4)));

// ---------------- K0: W[m][d][e] (fp32) -> WT[m][e][d] (bf16) ----------------
__global__ __launch_bounds__(256)
void prep_weights(const float* __restrict__ Wi, const float* __restrict__ We,
                  __hip_bfloat16* __restrict__ WiT, __hip_bfloat16* __restrict__ WeT) {
  __shared__ float tile[32][33];
  const int z = blockIdx.z;
  const float* src;
  __hip_bfloat16* dst;
  if (z < NM) { src = Wi + (size_t)z * ND * ND;        dst = WiT + (size_t)z * ND * ND; }
  else        { src = We + (size_t)(z - NM) * ND * ND; dst = WeT + (size_t)(z - NM) * ND * ND; }
  const int d0 = blockIdx.y * 32;
  const int e0 = blockIdx.x * 32;
  const int tx = threadIdx.x, ty = threadIdx.y;
  #pragma unroll
  for (int i = 0; i < 4; ++i)
    tile[ty + i * 8][tx] = src[(size_t)(d0 + ty + i * 8) * ND + e0 + tx];
  __syncthreads();
  #pragma unroll
  for (int i = 0; i < 4; ++i)
    dst[(size_t)(e0 + ty + i * 8) * ND + d0 + tx] = __float2bfloat16(tile[tx][ty + i * 8]);
}

// ---------------- K1: per-(btile,m) dual GEMM + sigmoid/L1 gate + relu ----------------
// 1-D grid 2304 with XCD-m clustering: XCD (bid&7) sweeps m slowly so the
// per-XCD L2 weight working set stays ~1-2MB (< 4MB) -> B-frag loads hit L2.
__global__ __launch_bounds__(NTHREADS, 4)
void gemm_kernel(const float* __restrict__ x,
                 const __hip_bfloat16* __restrict__ WiT,
                 const __hip_bfloat16* __restrict__ WeT,
                 const float* __restrict__ bi,
                 const float* __restrict__ be,
                 float* __restrict__ out) {
  __shared__ union {
    __hip_bfloat16 xs[BM][ND + 8];   // 1040B row stride: 16B aligned, 2-way banks
    __half         gs[BM][ND + 8];   // g repack buffer (reused after MFMAs)
  } sh;
  __shared__ float alphaW[8][BM];
  __shared__ float alphaV[BM];

  const int tid  = threadIdx.x;
  const int wave = tid >> 6;
  const int lane = tid & 63;
  const int l15  = lane & 15;
  const int l4   = lane >> 4;

  // XCD-m clustering decode (bijective: (m, bx) covers 9 x 256)
  const int bid = blockIdx.x;          // 0..2303
  const int q   = bid >> 3;            // 0..287
  const int m   = q >> 5;              // 0..8
  const int bx  = (bid & 7) + ((q & 31) << 3);
  const int b0  = bx * BM;
  const int wn0 = wave * 64;

  float* alpha_out = out + (size_t)BATCH * NM * ND;

  // ---- stage X tile: fp32 global -> bf16 LDS (once per block) ----
  #pragma unroll
  for (int it = 0; it < (BM * ND / 4) / NTHREADS; ++it) {
    int idx = it * NTHREADS + tid;
    int r   = idx >> 7;
    int c4  = (idx & 127) * 4;
    float4 v = *(const float4*)(x + (size_t)(b0 + r) * (NM * ND) + m * ND + c4);
    union { ushort4 u; __hip_bfloat16 h[4]; } p;
    p.h[0] = __float2bfloat16(v.x);
    p.h[1] = __float2bfloat16(v.y);
    p.h[2] = __float2bfloat16(v.z);
    p.h[3] = __float2bfloat16(v.w);
    *(ushort4*)&sh.xs[r][c4] = p.u;
  }
  __syncthreads();

  for (int pass = 0; pass < 2; ++pass) {
    const __hip_bfloat16* wbase = (pass ? WeT : WiT) + (size_t)m * ND * ND;
    const __hip_bfloat16* wp[4];
    #pragma unroll
    for (int nt = 0; nt < 4; ++nt)
      wp[nt] = wbase + (size_t)(wn0 + nt * 16 + l15) * ND + l4 * 8;

    f32x4 acc[4][4];
    #pragma unroll
    for (int a = 0; a < 4; ++a)
      #pragma unroll
      for (int c = 0; c < 4; ++c) acc[a][c] = (f32x4){0.f, 0.f, 0.f, 0.f};

    bf16x8 bcur[4], bnext[4];
    #pragma unroll
    for (int nt = 0; nt < 4; ++nt) bcur[nt] = *(const bf16x8*)(wp[nt]);

    #pragma unroll
    for (int kt = 0; kt < ND / 32; ++kt) {
      if (kt < ND / 32 - 1) {
        #pragma unroll
        for (int nt = 0; nt < 4; ++nt)
          bnext[nt] = *(const bf16x8*)(wp[nt] + (kt + 1) * 32);
      }
      bf16x8 af[4];
      const int kbase = kt * 32 + l4 * 8;
      #pragma unroll
      for (int mt = 0; mt < 4; ++mt)
        af[mt] = *(const bf16x8*)&sh.xs[mt * 16 + l15][kbase];
      #pragma unroll
      for (int mt = 0; mt < 4; ++mt)
        #pragma unroll
        for (int nt = 0; nt < 4; ++nt)
          acc[mt][nt] = __builtin_amdgcn_mfma_f32_16x16x32_bf16(af[mt], bcur[nt], acc[mt][nt], 0, 0, 0);
      #pragma unroll
      for (int nt = 0; nt < 4; ++nt) bcur[nt] = bnext[nt];
    }

    if (pass == 0) {
      // sigmoid + row-sum (sigmoid > 0 so |f| = f)
      float biv[4];
      #pragma unroll
      for (int nt = 0; nt < 4; ++nt) biv[nt] = bi[m * ND + wn0 + nt * 16 + l15];
      #pragma unroll
      for (int mt = 0; mt < 4; ++mt)
        #pragma unroll
        for (int r = 0; r < 4; ++r) {
          float s = 0.f;
          #pragma unroll
          for (int nt = 0; nt < 4; ++nt) {
            float t = acc[mt][nt][r] + biv[nt];
            s += 1.f / (1.f + __expf(-t));
          }
          s += __shfl_xor(s, 1, 16);
          s += __shfl_xor(s, 2, 16);
          s += __shfl_xor(s, 4, 16);
          s += __shfl_xor(s, 8, 16);
          if (l15 == 0) alphaW[wave][mt * 16 + l4 * 4 + r] = s;
        }
      __syncthreads();
      if (tid < BM) {
        float a = 0.f;
        #pragma unroll
        for (int w = 0; w < 8; ++w) a += alphaW[w][tid];
        alphaV[tid] = a;
        alpha_out[(size_t)(b0 + tid) * NM + m] = a;
      }
      __syncthreads();
    } else {
      // g = relu(alpha * t_e + be): repack via LDS, then coalesced 16B stores
      float bev[4];
      #pragma unroll
      for (int nt = 0; nt < 4; ++nt) bev[nt] = be[m * ND + wn0 + nt * 16 + l15];
      __syncthreads();   // all waves done reading sh.xs
      #pragma unroll
      for (int mt = 0; mt < 4; ++mt)
        #pragma unroll
        for (int r = 0; r < 4; ++r) {
          const int row = mt * 16 + l4 * 4 + r;
          const float al = alphaV[row];
          #pragma unroll
          for (int nt = 0; nt < 4; ++nt) {
            float t = fmaxf(al * acc[mt][nt][r] + bev[nt], 0.f);
            sh.gs[row][wn0 + nt * 16 + l15] = __float2half(t);
          }
        }
      __syncthreads();
      // wave w stores rows w, w+8, ..., w+56; each lane moves 16B (8 halves)
      #pragma unroll
      for (int i = 0; i < 8; ++i) {
        const int row = wave + i * 8;
        __half* gd = (__half*)((char*)out + (size_t)(b0 + row) * (NM * ND * 4)) + m * ND;
        *(uint4*)(gd + lane * 8) = *(const uint4*)&sh.gs[row][lane * 8];
      }
    }
  }
}

// ---------------- K2: inter-branch affinity + aggregation ----------------
__global__ __launch_bounds__(256)
void inter_kernel(float* __restrict__ out) {
  __shared__ float gs[NM][ND + 8];
  __shared__ float Gr[45];
  __shared__ float aff[NM][NM];
  const int b = blockIdx.x;
  const int tid = threadIdx.x;
  const __half* gsrc = (const __half*)((const char*)out + (size_t)b * (NM * ND * 4));

  for (int i = tid; i < NM * ND / 4; i += 256) {
    union { ushort4 u; __half h[4]; } p;
    p.u = *(const ushort4*)((const ushort*)gsrc + (size_t)i * 4);
    const int m = i >> 7;
    const int e = (i & 127) * 4;
    #pragma unroll
    for (int j = 0; j < 4; ++j) gs[m][e + j] = __half2float(p.h[j]);
  }
  __syncthreads();

  // 45 upper-triangular pair dot-products (incl. diagonal = sq)
  const int wave = tid >> 6, lane = tid & 63;
  for (int pr = wave; pr < 45; pr += 4) {
    int a = 0, qq = pr;
    while (qq >= NM - a) { qq -= NM - a; ++a; }
    const int bb = a + qq;
    float s = 0.f;
    #pragma unroll
    for (int j = 0; j < 8; ++j) s += gs[a][lane + 64 * j] * gs[bb][lane + 64 * j];
    #pragma unroll
    for (int off = 1; off < 64; off <<= 1) s += __shfl_xor(s, off, 64);
    if (lane == 0) Gr[pr] = s;
  }
  __syncthreads();

  if (tid < NM * NM) {
    const int mm = tid / NM, nn = tid % NM;
    float v = 0.f;
    if (mm != nn) {
      const int a = mm < nn ? mm : nn;
      const int c = mm < nn ? nn : mm;
      auto tri = [](int t) { return t * NM - (t * (t - 1)) / 2; };
      float d2 = Gr[tri(mm)] + Gr[tri(nn)] - 2.f * Gr[tri(a) + (c - a)];
      d2 = fmaxf(d2, 0.f);
      v = tanhf(sqrtf(d2));
    }
    aff[tid / NM][tid % NM] = v;
  }
  __syncthreads();

  float* od = out + (size_t)b * (NM * ND);
  for (int i = tid; i < NM * ND / 4; i += 256) {
    const int mm = i >> 7;
    const int e4 = (i & 127) * 4;
    float4 r;
    #pragma unroll
    for (int j = 0; j < 4; ++j) {
      const int e = e4 + j;
      float acc = 0.f;
      #pragma unroll
      for (int n = 0; n < NM; ++n) acc += aff[mm][n] * gs[n][e];
      ((float*)&r)[j] = 0.5f * (gs[mm][e] + acc);
    }
    *(float4*)(od + (size_t)mm * ND + e4) = r;
  }
}

extern "C" void kernel_launch(void* const* d_in, const int* in_sizes, int n_in,
                              void* d_out, int out_size, void* d_ws, size_t ws_size,
                              hipStream_t stream) {
  const float* x  = (const float*)d_in[0];
  const float* Wi = (const float*)d_in[1];
  const float* bi = (const float*)d_in[2];
  const float* We = (const float*)d_in[3];
  const float* be = (const float*)d_in[4];
  float* out = (float*)d_out;

  __hip_bfloat16* WiT = (__hip_bfloat16*)d_ws;
  __hip_bfloat16* WeT = WiT + (size_t)NM * ND * ND;

  prep_weights<<<dim3(ND / 32, ND / 32, 2 * NM), dim3(32, 8), 0, stream>>>(Wi, We, WiT, WeT);
  gemm_kernel<<<BATCH / BM * NM, NTHREADS, 0, stream>>>(x, WiT, WeT, bi, be, out);
  inter_kernel<<<BATCH, 256, 0, stream>>>(out);
}